// Round 8
// baseline (109.168 us; speedup 1.0000x reference)
//
#include <hip/hip_runtime.h>

#define NM 23        // 3*K - 1, K = 8

typedef short short8 __attribute__((ext_vector_type(8)));
typedef float f32x4 __attribute__((ext_vector_type(4)));

#define LOG2E 1.44269504088896340736f

__device__ __forceinline__ float softplus_f(float v) {
  return fmaxf(v, 0.f) + __logf(1.f + __expf(-fabsf(v)));
}

__device__ __forceinline__ float fastrcp(float v) {
  return __builtin_amdgcn_rcpf(v);   // v_rcp_f32, ~1-2 ulp
}

__device__ __forceinline__ unsigned short bf16_rne(float x) {
  unsigned u = __float_as_uint(x);
  u += 0x7FFFu + ((u >> 16) & 1u);
  return (unsigned short)(u >> 16);
}

// ---------------------------------------------------------------------------
// Prep (R21-validated). W3 rows m<16 pre-scaled by log2(e) -> exp2 domain.
// Fragment layout: B[k][n], n = ntile*16 + (lane&15),
// k = kstep*32 + (lane>>4)*8 + j, stored at ((ntile*nk+kstep)*64+lane)*8+j.
// ---------------------------------------------------------------------------
__global__ __launch_bounds__(256) void prep_kernel(
    const float* __restrict__ W1, const float* __restrict__ W2,
    const float* __restrict__ W3,
    unsigned short* __restrict__ B1hi, unsigned short* __restrict__ B1lo,
    unsigned short* __restrict__ B2hi, unsigned short* __restrict__ B2lo,
    unsigned short* __restrict__ B3hi, unsigned short* __restrict__ B3lo) {
  const int idx = blockIdx.x * 256 + threadIdx.x;
  const int j = idx & 7, lane = (idx >> 3) & 63;
  const int col = lane & 15, quad = lane >> 4;

  if (idx < 4096) {                     // W1 fragments: nt<4, kt<2
    const int rest = idx >> 9, kt = rest & 1, nt = rest >> 1;
    const int k = kt * 32 + quad * 8 + j;   // d
    const int n = nt * 16 + col;            // i
    const float v = ((n % 63) >= k) ? W1[n * 64 + k] : 0.f;
    const unsigned short h = bf16_rne(v);
    B1hi[idx] = h;
    B1lo[idx] = bf16_rne(v - __uint_as_float(((unsigned)h) << 16));
  }
  if (idx < 2048) {                     // W2 fragments: nt<2, kt<2
    const int rest = idx >> 9, kt = rest & 1, nt = rest >> 1;
    const int k = kt * 32 + quad * 8 + j;   // i
    const int n = nt * 16 + col;            // j
    const float v = ((k % 63) <= n) ? W2[n * 64 + k] : 0.f;
    const unsigned short h = bf16_rne(v);
    B2hi[idx] = h;
    B2lo[idx] = bf16_rne(v - __uint_as_float(((unsigned)h) << 16));
  }
  if (idx < 92 * 64 * 8) {              // W3 fragments
    const int nt = idx >> 9;
    const int n = nt * 16 + col;        // n = m*64 + d
    const int d = n & 63;
    const int m = n >> 6;
    const int k = quad * 8 + j;
    float v = (k < d) ? W3[(size_t)n * 32 + k] : 0.f;
    if (m < 16) v *= LOG2E;             // exp2 domain for softmax logits
    const unsigned short h = bf16_rne(v);
    B3hi[idx] = h;
    B3lo[idx] = bf16_rne(v - __uint_as_float(((unsigned)h) << 16));
  }
}

// f32x4 pair (LDS or global, 16B-aligned) -> bf16 hi/lo fragment
__device__ __forceinline__ void cvt_hilo(const float* src, short8& hi,
                                         short8& lo) {
  const f32x4 a0 = *reinterpret_cast<const f32x4*>(src);
  const f32x4 a1 = *reinterpret_cast<const f32x4*>(src + 4);
  const float af[8] = {a0.x, a0.y, a0.z, a0.w, a1.x, a1.y, a1.z, a1.w};
  #pragma unroll
  for (int j = 0; j < 8; ++j) {
    const unsigned short h = bf16_rne(af[j]);
    hi[j] = (short)h;
    lo[j] = (short)bf16_rne(af[j] - __uint_as_float(((unsigned)h) << 16));
  }
}

// ---------------------------------------------------------------------------
// Fused kernel. R22 CHANGE (R21 post-mortem: supply reached 32 waves/CU but
// measured residency stuck at ~10.5 — block granularity or hidden AGPR
// footprint caps co-residency of 8-wave blocks):
//   (a) HALF-SIZE BLOCKS: 16-row x 64-col, 256 threads (4 waves), grid
//       B/16 = 2048 = 8 blocks/CU supply. Same balanced wave mapping:
//       L1 = 4 n-tiles -> 4 waves (still ZERO MLP duplication), L2 = 2
//       tiles -> 2 waves, L3 = 4 d-chunks -> 4 waves, 4 points/lane.
//       LDS 15 KB -> 10 blocks/CU LDS-wise; cheaper co-scheduling.
//   (b) constant-folded softmax prefix: cumw[k+1] = fmaf(prefE, scale, C_k)
//       with scale = 6*WSC*rcp(sum) hoisted, C_k compile-time
//       (-28 VALU/point). Same values modulo fp association; spline is
//       continuous at knots so edge flips are value-continuous.
// Everything else identical to R21 (validated).
// ---------------------------------------------------------------------------
__global__ __launch_bounds__(256, 4) void fused_kernel(
    const float* __restrict__ x,
    const unsigned short* __restrict__ B1hi,
    const unsigned short* __restrict__ B1lo,
    const float* __restrict__ b1,
    const unsigned short* __restrict__ B2hi,
    const unsigned short* __restrict__ B2lo,
    const float* __restrict__ b2,
    const unsigned short* __restrict__ B3hi,
    const unsigned short* __restrict__ B3lo,
    const float* __restrict__ b3,
    float* __restrict__ out, int B) {
  __shared__ float h1s[16][68];    // stride 68: 16B-aligned b128 A-frag reads
  __shared__ float h2s[16][68];    // h2 (cols 0..31) -> z (cols 0..63)
  __shared__ float b3s[64 * NM];   // biases [d][m], W/H pre-scaled by log2e
  __shared__ float ldp[4][16];     // per-dc log-det partials

  const int t = threadIdx.x;
  const int b0 = blockIdx.x * 16;

  // ---- stage b3: b3s[d*NM+m] = b3[m*64+d] (*log2e for m<16) ----
  for (int idx = t; idx < 64 * NM; idx += 256) {
    const int dl = idx / NM, m = idx - dl * NM;
    const float s = (m < 16) ? LOG2E : 1.f;
    b3s[idx] = b3[m * 64 + dl] * s;
  }
  __syncthreads();                 // B1: b3 staged

  const int lane = t & 63;
  const int wv   = __builtin_amdgcn_readfirstlane(t >> 6);  // wave 0..3
  const int col  = lane & 15;
  const int quad = lane >> 4;

  // ---- layer 1 (MFMA): tile nt1 = wv, A-frags from global x ----
  {
    const int nt1 = wv;
    const float* xrow = x + (size_t)(b0 + col) * 64;
    short8 ahi[2], alo[2];
    #pragma unroll
    for (int kt = 0; kt < 2; ++kt)
      cvt_hilo(xrow + kt * 32 + quad * 8, ahi[kt], alo[kt]);

    const float bv = b1[nt1 * 16 + col];
    f32x4 acc = {bv, bv, bv, bv};
    #pragma unroll
    for (int kt = 0; kt < 2; ++kt) {
      const size_t off = ((size_t)(nt1 * 2 + kt) * 64 + lane) * 8;
      const short8 bh = *reinterpret_cast<const short8*>(B1hi + off);
      const short8 bl = *reinterpret_cast<const short8*>(B1lo + off);
      acc = __builtin_amdgcn_mfma_f32_16x16x32_bf16(ahi[kt], bh, acc, 0, 0, 0);
      acc = __builtin_amdgcn_mfma_f32_16x16x32_bf16(alo[kt], bh, acc, 0, 0, 0);
      acc = __builtin_amdgcn_mfma_f32_16x16x32_bf16(ahi[kt], bl, acc, 0, 0, 0);
    }
    #pragma unroll
    for (int reg = 0; reg < 4; ++reg)
      h1s[quad * 4 + reg][nt1 * 16 + col] = fmaxf(acc[reg], 0.f);
  }
  __syncthreads();                 // B2: h1 complete

  // ---- layer 2 (MFMA): tile nt2, waves 0..1 ----
  if (wv < 2) {
    const int nt2 = wv;
    short8 ahi[2], alo[2];
    #pragma unroll
    for (int kt = 0; kt < 2; ++kt)
      cvt_hilo(&h1s[col][kt * 32 + quad * 8], ahi[kt], alo[kt]);

    const float bv = b2[nt2 * 16 + col];
    f32x4 acc = {bv, bv, bv, bv};
    #pragma unroll
    for (int kt = 0; kt < 2; ++kt) {
      const size_t off = ((size_t)(nt2 * 2 + kt) * 64 + lane) * 8;
      const short8 bh = *reinterpret_cast<const short8*>(B2hi + off);
      const short8 bl = *reinterpret_cast<const short8*>(B2lo + off);
      acc = __builtin_amdgcn_mfma_f32_16x16x32_bf16(ahi[kt], bh, acc, 0, 0, 0);
      acc = __builtin_amdgcn_mfma_f32_16x16x32_bf16(alo[kt], bh, acc, 0, 0, 0);
      acc = __builtin_amdgcn_mfma_f32_16x16x32_bf16(ahi[kt], bl, acc, 0, 0, 0);
    }
    #pragma unroll
    for (int reg = 0; reg < 4; ++reg)
      h2s[quad * 4 + reg][nt2 * 16 + col] = fmaxf(acc[reg], 0.f);
  }
  __syncthreads();                 // B3: h2 complete

  // ---- layer 3 setup: wave = dc; hoist A-frag + x before z writes ----
  const int dc = wv;
  const int row0 = quad * 4;
  const int d = dc * 16 + col;

  short8 ahi, alo;
  cvt_hilo(&h2s[col][quad * 8], ahi, alo);

  float xvv[4];
  #pragma unroll
  for (int reg = 0; reg < 4; ++reg)
    xvv[reg] = x[(size_t)(b0 + row0 + reg) * 64 + d];

  __syncthreads();                 // B4: A-frags hoisted; h2s free for z

  float ldr[4] = {0.f, 0.f, 0.f, 0.f};
  const float WSC = 1.0f - 1e-3f * 8.0f;

  float xcv[4], fidx[4], xkv[4], wkv[4], ykv[4], hkv[4];

  // ======== group W: m in [0,8) -> xc, idx, xk, wk ========
  {
    f32x4 acc[8];
    #pragma unroll
    for (int m = 0; m < 8; ++m) {
      const float bv = b3s[d * NM + m];
      acc[m] = (f32x4){bv, bv, bv, bv};
    }
    #pragma unroll
    for (int m = 0; m < 8; ++m) {
      const size_t off = ((size_t)(4 * m + dc) * 64 + lane) * 8;
      const short8 bh = *reinterpret_cast<const short8*>(B3hi + off);
      const short8 bl = *reinterpret_cast<const short8*>(B3lo + off);
      acc[m] = __builtin_amdgcn_mfma_f32_16x16x32_bf16(ahi, bh, acc[m], 0, 0, 0);
      acc[m] = __builtin_amdgcn_mfma_f32_16x16x32_bf16(alo, bh, acc[m], 0, 0, 0);
      acc[m] = __builtin_amdgcn_mfma_f32_16x16x32_bf16(ahi, bl, acc[m], 0, 0, 0);
    }
    #pragma unroll
    for (int reg = 0; reg < 4; ++reg) {
      float ew[8], sw = 0.f;
      #pragma unroll
      for (int k = 0; k < 8; ++k) { ew[k] = exp2f(acc[k][reg]); sw += ew[k]; }
      const float scale = 6.f * WSC * fastrcp(sw);
      float cumw[9];
      cumw[0] = -3.f;
      float prefE = 0.f;
      #pragma unroll
      for (int k = 0; k < 7; ++k) {
        prefE += ew[k];
        const float Ck = -3.f + 6e-3f * (float)(k + 1);
        cumw[k + 1] = fmaf(prefE, scale, Ck);
      }
      cumw[8] = 3.f;

      const float xv = xvv[reg];
      const float xc = fminf(fmaxf(xv, -3.f), 3.f);
      float fi = 0.f, xk = cumw[0], xk1 = cumw[1];
      #pragma unroll
      for (int k = 1; k < 8; ++k) {
        const bool s = xc >= cumw[k] + 1e-6f;
        xk  = s ? cumw[k]     : xk;
        xk1 = s ? cumw[k + 1] : xk1;
        fi  = s ? (float)k    : fi;
      }
      xcv[reg] = xc; fidx[reg] = fi; xkv[reg] = xk; wkv[reg] = xk1 - xk;
    }
  }

  // ======== group H: m in [8,16) -> yk, hk ========
  {
    f32x4 acc[8];
    #pragma unroll
    for (int m = 0; m < 8; ++m) {
      const float bv = b3s[d * NM + (8 + m)];
      acc[m] = (f32x4){bv, bv, bv, bv};
    }
    #pragma unroll
    for (int m = 0; m < 8; ++m) {
      const size_t off = ((size_t)(4 * (8 + m) + dc) * 64 + lane) * 8;
      const short8 bh = *reinterpret_cast<const short8*>(B3hi + off);
      const short8 bl = *reinterpret_cast<const short8*>(B3lo + off);
      acc[m] = __builtin_amdgcn_mfma_f32_16x16x32_bf16(ahi, bh, acc[m], 0, 0, 0);
      acc[m] = __builtin_amdgcn_mfma_f32_16x16x32_bf16(alo, bh, acc[m], 0, 0, 0);
      acc[m] = __builtin_amdgcn_mfma_f32_16x16x32_bf16(ahi, bl, acc[m], 0, 0, 0);
    }
    #pragma unroll
    for (int reg = 0; reg < 4; ++reg) {
      float eh[8], sh = 0.f;
      #pragma unroll
      for (int k = 0; k < 8; ++k) { eh[k] = exp2f(acc[k][reg]); sh += eh[k]; }
      const float scale = 6.f * WSC * fastrcp(sh);
      float cumh[9];
      cumh[0] = -3.f;
      float prefE = 0.f;
      #pragma unroll
      for (int k = 0; k < 7; ++k) {
        prefE += eh[k];
        const float Ck = -3.f + 6e-3f * (float)(k + 1);
        cumh[k + 1] = fmaf(prefE, scale, Ck);
      }
      cumh[8] = 3.f;

      float yk = cumh[0], yk1 = cumh[1];
      #pragma unroll
      for (int k = 1; k < 8; ++k) {
        const bool s = fidx[reg] >= (float)k;
        yk  = s ? cumh[k]     : yk;
        yk1 = s ? cumh[k + 1] : yk1;
      }
      ykv[reg] = yk; hkv[reg] = yk1 - yk;
    }
  }

  // ======== group D: m in [16,23) -> dk, dk1 + final spline ========
  {
    f32x4 acc[7];
    #pragma unroll
    for (int m = 0; m < 7; ++m) {
      const float bv = b3s[d * NM + (16 + m)];
      acc[m] = (f32x4){bv, bv, bv, bv};
    }
    #pragma unroll
    for (int m = 0; m < 7; ++m) {
      const size_t off = ((size_t)(4 * (16 + m) + dc) * 64 + lane) * 8;
      const short8 bh = *reinterpret_cast<const short8*>(B3hi + off);
      const short8 bl = *reinterpret_cast<const short8*>(B3lo + off);
      acc[m] = __builtin_amdgcn_mfma_f32_16x16x32_bf16(ahi, bh, acc[m], 0, 0, 0);
      acc[m] = __builtin_amdgcn_mfma_f32_16x16x32_bf16(alo, bh, acc[m], 0, 0, 0);
      acc[m] = __builtin_amdgcn_mfma_f32_16x16x32_bf16(ahi, bl, acc[m], 0, 0, 0);
    }
    #pragma unroll
    for (int reg = 0; reg < 4; ++reg) {
      float p[7];
      #pragma unroll
      for (int k = 0; k < 7; ++k) p[k] = acc[k][reg];
      const float fi = fidx[reg];

      // dk  = idx==0 ? 1 : 1e-3+sp(p[idx-1]);  dk1 = idx==7 ? 1 : 1e-3+sp(p[idx])
      float pa = p[0], pb = p[0];
      #pragma unroll
      for (int k = 2; k < 8; ++k) pa = (fi >= (float)k) ? p[k - 1] : pa;
      #pragma unroll
      for (int k = 1; k < 7; ++k) pb = (fi >= (float)k) ? p[k] : pb;
      const float spa = 1e-3f + softplus_f(pa);
      const float spb = 1e-3f + softplus_f(pb);
      const float dk  = (fi >= 0.5f) ? spa : 1.f;
      const float dk1 = (fi >= 6.5f) ? 1.f : spb;

      const float xc = xcv[reg], xk = xkv[reg], wk = wkv[reg];
      const float yk = ykv[reg], hk = hkv[reg];
      const float invwk = fastrcp(wk);
      const float delta = hk * invwk;
      const float theta = (xc - xk) * invwk;
      const float omt = 1.f - theta;
      const float tt = theta * omt;
      const float th2 = theta * theta;
      const float num = hk * (delta * th2 + dk * tt);
      const float den = delta + (dk + dk1 - 2.f * delta) * tt;
      const float rden = fastrcp(den);
      const float yv = yk + num * rden;
      const float dnum =
          delta * delta * (dk1 * th2 + 2.f * delta * tt + dk * omt * omt);
      const float ldv = __logf(dnum * rden * rden);

      const float xv = xvv[reg];
      const bool inside = (xv >= -3.f) && (xv <= 3.f);
      h2s[row0 + reg][d] = inside ? yv : xv;    // z into LDS (h2s reuse)
      ldr[reg] += inside ? ldv : 0.f;
    }
  }

  // ---- log-det: reduce this wave's 16 cols (lane bits 0..3) ----
  #pragma unroll
  for (int mask = 1; mask <= 8; mask <<= 1) {
    #pragma unroll
    for (int reg = 0; reg < 4; ++reg)
      ldr[reg] += __shfl_xor(ldr[reg], mask, 64);
  }
  if (col == 0) {
    #pragma unroll
    for (int reg = 0; reg < 4; ++reg)
      ldp[dc][row0 + reg] = ldr[reg];
  }

  __syncthreads();                 // B5: z + ld partials done

  // ---- ld: complete 64-d sum per row ----
  if (t < 16)
    out[(size_t)B * 64 + b0 + t] =
        (ldp[0][t] + ldp[1][t]) + (ldp[2][t] + ldp[3][t]);

  // ---- coalesced z write: 16 rows x 64 cols, 1 float4/thread ----
  {
    const int rr = t >> 4, c4 = (t & 15) * 4;
    const float4 v = make_float4(h2s[rr][c4 + 0], h2s[rr][c4 + 1],
                                 h2s[rr][c4 + 2], h2s[rr][c4 + 3]);
    *reinterpret_cast<float4*>(out + (size_t)(b0 + rr) * 64 + c4) = v;
  }
}

extern "C" void kernel_launch(void* const* d_in, const int* in_sizes, int n_in,
                              void* d_out, int out_size, void* d_ws, size_t ws_size,
                              hipStream_t stream) {
  const float* x  = (const float*)d_in[0];
  const float* W1 = (const float*)d_in[1];
  const float* b1 = (const float*)d_in[2];
  const float* W2 = (const float*)d_in[3];
  const float* b2 = (const float*)d_in[4];
  const float* W3 = (const float*)d_in[5];
  const float* b3 = (const float*)d_in[6];
  float* out = (float*)d_out;
  char* ws   = (char*)d_ws;

  unsigned short* B1hi = (unsigned short*)(ws);           // 4096 u16
  unsigned short* B1lo = (unsigned short*)(ws + 8192);    // 4096 u16
  unsigned short* B2hi = (unsigned short*)(ws + 16384);   // 2048 u16
  unsigned short* B2lo = (unsigned short*)(ws + 20480);   // 2048 u16
  unsigned short* B3hi = (unsigned short*)(ws + 24576);   // 47104 u16
  unsigned short* B3lo = (unsigned short*)(ws + 118784);  // 47104 u16

  const int B = in_sizes[0] / 64;        // 32768

  prep_kernel<<<184, 256, 0, stream>>>(W1, W2, W3, B1hi, B1lo, B2hi, B2lo,
                                       B3hi, B3lo);

  fused_kernel<<<B / 16, 256, 0, stream>>>(
      x, B1hi, B1lo, b1, B2hi, B2lo, b2, B3hi, B3lo, b3, out, B);
}

// Round 10
// 106.319 us; speedup vs baseline: 1.0268x; 1.0268x over previous
//
#include <hip/hip_runtime.h>

#define NM 23        // 3*K - 1, K = 8

typedef short short8 __attribute__((ext_vector_type(8)));
typedef float f32x4 __attribute__((ext_vector_type(4)));

#define LOG2E 1.44269504088896340736f

__device__ __forceinline__ float softplus_f(float v) {
  return fmaxf(v, 0.f) + __logf(1.f + __expf(-fabsf(v)));
}

__device__ __forceinline__ float fastrcp(float v) {
  return __builtin_amdgcn_rcpf(v);   // v_rcp_f32, ~1-2 ulp
}

__device__ __forceinline__ unsigned short bf16_rne(float x) {
  unsigned u = __float_as_uint(x);
  u += 0x7FFFu + ((u >> 16) & 1u);
  return (unsigned short)(u >> 16);
}

// ---------------------------------------------------------------------------
// Prep. R24: B-side LOW WORD DROPPED (2-pass hi/lo: ahi*bh + alo*bh).
// The dropped ahi*bl term is <= |a|*2^-9|b| per product; ~1e-3 absolute on
// p over K=32 — far below the bf16-ULP output floor (0.0156, threshold
// 0.1725). Only Bhi fragments are emitted now.
// W3 rows m<16 pre-scaled by log2(e) -> exp2 domain (R21-validated).
// Fragment layout: B[k][n], n = ntile*16 + (lane&15),
// k = kstep*32 + (lane>>4)*8 + j, stored at ((ntile*nk+kstep)*64+lane)*8+j.
// ---------------------------------------------------------------------------
__global__ __launch_bounds__(256) void prep_kernel(
    const float* __restrict__ W1, const float* __restrict__ W2,
    const float* __restrict__ W3,
    unsigned short* __restrict__ B1hi,
    unsigned short* __restrict__ B2hi,
    unsigned short* __restrict__ B3hi) {
  const int idx = blockIdx.x * 256 + threadIdx.x;
  const int j = idx & 7, lane = (idx >> 3) & 63;
  const int col = lane & 15, quad = lane >> 4;

  if (idx < 4096) {                     // W1 fragments: nt<4, kt<2
    const int rest = idx >> 9, kt = rest & 1, nt = rest >> 1;
    const int k = kt * 32 + quad * 8 + j;   // d
    const int n = nt * 16 + col;            // i
    const float v = ((n % 63) >= k) ? W1[n * 64 + k] : 0.f;
    B1hi[idx] = bf16_rne(v);
  }
  if (idx < 2048) {                     // W2 fragments: nt<2, kt<2
    const int rest = idx >> 9, kt = rest & 1, nt = rest >> 1;
    const int k = kt * 32 + quad * 8 + j;   // i
    const int n = nt * 16 + col;            // j
    const float v = ((k % 63) <= n) ? W2[n * 64 + k] : 0.f;
    B2hi[idx] = bf16_rne(v);
  }
  if (idx < 92 * 64 * 8) {              // W3 fragments
    const int nt = idx >> 9;
    const int n = nt * 16 + col;        // n = m*64 + d
    const int d = n & 63;
    const int m = n >> 6;
    const int k = quad * 8 + j;
    float v = (k < d) ? W3[(size_t)n * 32 + k] : 0.f;
    if (m < 16) v *= LOG2E;             // exp2 domain for softmax logits
    B3hi[idx] = bf16_rne(v);
  }
}

// f32x4 pair (LDS or global, 16B-aligned) -> bf16 hi/lo fragment
__device__ __forceinline__ void cvt_hilo(const float* src, short8& hi,
                                         short8& lo) {
  const f32x4 a0 = *reinterpret_cast<const f32x4*>(src);
  const f32x4 a1 = *reinterpret_cast<const f32x4*>(src + 4);
  const float af[8] = {a0.x, a0.y, a0.z, a0.w, a1.x, a1.y, a1.z, a1.w};
  #pragma unroll
  for (int j = 0; j < 8; ++j) {
    const unsigned short h = bf16_rne(af[j]);
    hi[j] = (short)h;
    lo[j] = (short)bf16_rne(af[j] - __uint_as_float(((unsigned)h) << 16));
  }
}

// ---------------------------------------------------------------------------
// Fused kernel. R24 = R22 (last-known-good, validated) + B-lo dropped:
// every MFMA site is now  acc = mfma(ahi,bh) ; acc = mfma(alo,bh)  —
// per m-step: 1 load instead of 2, 2 MFMA instead of 3. This halves the
// ~188 MB/launch L2 B-fragment stream (the dominant dependent-latency
// source identified in R22's post-mortem) and cuts MFMA issue 33%.
// R23's masked-sum softmax rewrite REVERTED (failed, mechanism unexplained).
// All control flow, barriers, and per-point spline math identical to R22.
// ---------------------------------------------------------------------------
__global__ __launch_bounds__(256, 4) void fused_kernel(
    const float* __restrict__ x,
    const unsigned short* __restrict__ B1hi,
    const float* __restrict__ b1,
    const unsigned short* __restrict__ B2hi,
    const float* __restrict__ b2,
    const unsigned short* __restrict__ B3hi,
    const float* __restrict__ b3,
    float* __restrict__ out, int B) {
  __shared__ float h1s[16][68];    // stride 68: 16B-aligned b128 A-frag reads
  __shared__ float h2s[16][68];    // h2 (cols 0..31) -> z (cols 0..63)
  __shared__ float b3s[64 * NM];   // biases [d][m], W/H pre-scaled by log2e
  __shared__ float ldp[4][16];     // per-dc log-det partials

  const int t = threadIdx.x;
  const int b0 = blockIdx.x * 16;

  // ---- stage b3: b3s[d*NM+m] = b3[m*64+d] (*log2e for m<16) ----
  for (int idx = t; idx < 64 * NM; idx += 256) {
    const int dl = idx / NM, m = idx - dl * NM;
    const float s = (m < 16) ? LOG2E : 1.f;
    b3s[idx] = b3[m * 64 + dl] * s;
  }
  __syncthreads();                 // B1: b3 staged

  const int lane = t & 63;
  const int wv   = __builtin_amdgcn_readfirstlane(t >> 6);  // wave 0..3
  const int col  = lane & 15;
  const int quad = lane >> 4;

  // ---- layer 1 (MFMA): tile nt1 = wv, A-frags from global x ----
  {
    const int nt1 = wv;
    const float* xrow = x + (size_t)(b0 + col) * 64;
    short8 ahi[2], alo[2];
    #pragma unroll
    for (int kt = 0; kt < 2; ++kt)
      cvt_hilo(xrow + kt * 32 + quad * 8, ahi[kt], alo[kt]);

    const float bv = b1[nt1 * 16 + col];
    f32x4 acc = {bv, bv, bv, bv};
    #pragma unroll
    for (int kt = 0; kt < 2; ++kt) {
      const size_t off = ((size_t)(nt1 * 2 + kt) * 64 + lane) * 8;
      const short8 bh = *reinterpret_cast<const short8*>(B1hi + off);
      acc = __builtin_amdgcn_mfma_f32_16x16x32_bf16(ahi[kt], bh, acc, 0, 0, 0);
      acc = __builtin_amdgcn_mfma_f32_16x16x32_bf16(alo[kt], bh, acc, 0, 0, 0);
    }
    #pragma unroll
    for (int reg = 0; reg < 4; ++reg)
      h1s[quad * 4 + reg][nt1 * 16 + col] = fmaxf(acc[reg], 0.f);
  }
  __syncthreads();                 // B2: h1 complete

  // ---- layer 2 (MFMA): tile nt2, waves 0..1 ----
  if (wv < 2) {
    const int nt2 = wv;
    short8 ahi[2], alo[2];
    #pragma unroll
    for (int kt = 0; kt < 2; ++kt)
      cvt_hilo(&h1s[col][kt * 32 + quad * 8], ahi[kt], alo[kt]);

    const float bv = b2[nt2 * 16 + col];
    f32x4 acc = {bv, bv, bv, bv};
    #pragma unroll
    for (int kt = 0; kt < 2; ++kt) {
      const size_t off = ((size_t)(nt2 * 2 + kt) * 64 + lane) * 8;
      const short8 bh = *reinterpret_cast<const short8*>(B2hi + off);
      acc = __builtin_amdgcn_mfma_f32_16x16x32_bf16(ahi[kt], bh, acc, 0, 0, 0);
      acc = __builtin_amdgcn_mfma_f32_16x16x32_bf16(alo[kt], bh, acc, 0, 0, 0);
    }
    #pragma unroll
    for (int reg = 0; reg < 4; ++reg)
      h2s[quad * 4 + reg][nt2 * 16 + col] = fmaxf(acc[reg], 0.f);
  }
  __syncthreads();                 // B3: h2 complete

  // ---- layer 3 setup: wave = dc; hoist A-frag + x before z writes ----
  const int dc = wv;
  const int row0 = quad * 4;
  const int d = dc * 16 + col;

  short8 ahi, alo;
  cvt_hilo(&h2s[col][quad * 8], ahi, alo);

  float xvv[4];
  #pragma unroll
  for (int reg = 0; reg < 4; ++reg)
    xvv[reg] = x[(size_t)(b0 + row0 + reg) * 64 + d];

  __syncthreads();                 // B4: A-frags hoisted; h2s free for z

  float ldr[4] = {0.f, 0.f, 0.f, 0.f};
  const float WSC = 1.0f - 1e-3f * 8.0f;

  float xcv[4], fidx[4], xkv[4], wkv[4], ykv[4], hkv[4];

  // ======== group W: m in [0,8) -> xc, idx, xk, wk ========
  {
    f32x4 acc[8];
    #pragma unroll
    for (int m = 0; m < 8; ++m) {
      const float bv = b3s[d * NM + m];
      acc[m] = (f32x4){bv, bv, bv, bv};
    }
    #pragma unroll
    for (int m = 0; m < 8; ++m) {
      const size_t off = ((size_t)(4 * m + dc) * 64 + lane) * 8;
      const short8 bh = *reinterpret_cast<const short8*>(B3hi + off);
      acc[m] = __builtin_amdgcn_mfma_f32_16x16x32_bf16(ahi, bh, acc[m], 0, 0, 0);
      acc[m] = __builtin_amdgcn_mfma_f32_16x16x32_bf16(alo, bh, acc[m], 0, 0, 0);
    }
    #pragma unroll
    for (int reg = 0; reg < 4; ++reg) {
      float ew[8], sw = 0.f;
      #pragma unroll
      for (int k = 0; k < 8; ++k) { ew[k] = exp2f(acc[k][reg]); sw += ew[k]; }
      const float scale = 6.f * WSC * fastrcp(sw);
      float cumw[9];
      cumw[0] = -3.f;
      float prefE = 0.f;
      #pragma unroll
      for (int k = 0; k < 7; ++k) {
        prefE += ew[k];
        const float Ck = -3.f + 6e-3f * (float)(k + 1);
        cumw[k + 1] = fmaf(prefE, scale, Ck);
      }
      cumw[8] = 3.f;

      const float xv = xvv[reg];
      const float xc = fminf(fmaxf(xv, -3.f), 3.f);
      float fi = 0.f, xk = cumw[0], xk1 = cumw[1];
      #pragma unroll
      for (int k = 1; k < 8; ++k) {
        const bool s = xc >= cumw[k] + 1e-6f;
        xk  = s ? cumw[k]     : xk;
        xk1 = s ? cumw[k + 1] : xk1;
        fi  = s ? (float)k    : fi;
      }
      xcv[reg] = xc; fidx[reg] = fi; xkv[reg] = xk; wkv[reg] = xk1 - xk;
    }
  }

  // ======== group H: m in [8,16) -> yk, hk ========
  {
    f32x4 acc[8];
    #pragma unroll
    for (int m = 0; m < 8; ++m) {
      const float bv = b3s[d * NM + (8 + m)];
      acc[m] = (f32x4){bv, bv, bv, bv};
    }
    #pragma unroll
    for (int m = 0; m < 8; ++m) {
      const size_t off = ((size_t)(4 * (8 + m) + dc) * 64 + lane) * 8;
      const short8 bh = *reinterpret_cast<const short8*>(B3hi + off);
      acc[m] = __builtin_amdgcn_mfma_f32_16x16x32_bf16(ahi, bh, acc[m], 0, 0, 0);
      acc[m] = __builtin_amdgcn_mfma_f32_16x16x32_bf16(alo, bh, acc[m], 0, 0, 0);
    }
    #pragma unroll
    for (int reg = 0; reg < 4; ++reg) {
      float eh[8], sh = 0.f;
      #pragma unroll
      for (int k = 0; k < 8; ++k) { eh[k] = exp2f(acc[k][reg]); sh += eh[k]; }
      const float scale = 6.f * WSC * fastrcp(sh);
      float cumh[9];
      cumh[0] = -3.f;
      float prefE = 0.f;
      #pragma unroll
      for (int k = 0; k < 7; ++k) {
        prefE += eh[k];
        const float Ck = -3.f + 6e-3f * (float)(k + 1);
        cumh[k + 1] = fmaf(prefE, scale, Ck);
      }
      cumh[8] = 3.f;

      float yk = cumh[0], yk1 = cumh[1];
      #pragma unroll
      for (int k = 1; k < 8; ++k) {
        const bool s = fidx[reg] >= (float)k;
        yk  = s ? cumh[k]     : yk;
        yk1 = s ? cumh[k + 1] : yk1;
      }
      ykv[reg] = yk; hkv[reg] = yk1 - yk;
    }
  }

  // ======== group D: m in [16,23) -> dk, dk1 + final spline ========
  {
    f32x4 acc[7];
    #pragma unroll
    for (int m = 0; m < 7; ++m) {
      const float bv = b3s[d * NM + (16 + m)];
      acc[m] = (f32x4){bv, bv, bv, bv};
    }
    #pragma unroll
    for (int m = 0; m < 7; ++m) {
      const size_t off = ((size_t)(4 * (16 + m) + dc) * 64 + lane) * 8;
      const short8 bh = *reinterpret_cast<const short8*>(B3hi + off);
      acc[m] = __builtin_amdgcn_mfma_f32_16x16x32_bf16(ahi, bh, acc[m], 0, 0, 0);
      acc[m] = __builtin_amdgcn_mfma_f32_16x16x32_bf16(alo, bh, acc[m], 0, 0, 0);
    }
    #pragma unroll
    for (int reg = 0; reg < 4; ++reg) {
      float p[7];
      #pragma unroll
      for (int k = 0; k < 7; ++k) p[k] = acc[k][reg];
      const float fi = fidx[reg];

      // dk  = idx==0 ? 1 : 1e-3+sp(p[idx-1]);  dk1 = idx==7 ? 1 : 1e-3+sp(p[idx])
      float pa = p[0], pb = p[0];
      #pragma unroll
      for (int k = 2; k < 8; ++k) pa = (fi >= (float)k) ? p[k - 1] : pa;
      #pragma unroll
      for (int k = 1; k < 7; ++k) pb = (fi >= (float)k) ? p[k] : pb;
      const float spa = 1e-3f + softplus_f(pa);
      const float spb = 1e-3f + softplus_f(pb);
      const float dk  = (fi >= 0.5f) ? spa : 1.f;
      const float dk1 = (fi >= 6.5f) ? 1.f : spb;

      const float xc = xcv[reg], xk = xkv[reg], wk = wkv[reg];
      const float yk = ykv[reg], hk = hkv[reg];
      const float invwk = fastrcp(wk);
      const float delta = hk * invwk;
      const float theta = (xc - xk) * invwk;
      const float omt = 1.f - theta;
      const float tt = theta * omt;
      const float th2 = theta * theta;
      const float num = hk * (delta * th2 + dk * tt);
      const float den = delta + (dk + dk1 - 2.f * delta) * tt;
      const float rden = fastrcp(den);
      const float yv = yk + num * rden;
      const float dnum =
          delta * delta * (dk1 * th2 + 2.f * delta * tt + dk * omt * omt);
      const float ldv = __logf(dnum * rden * rden);

      const float xv = xvv[reg];
      const bool inside = (xv >= -3.f) && (xv <= 3.f);
      h2s[row0 + reg][d] = inside ? yv : xv;    // z into LDS (h2s reuse)
      ldr[reg] += inside ? ldv : 0.f;
    }
  }

  // ---- log-det: reduce this wave's 16 cols (lane bits 0..3) ----
  #pragma unroll
  for (int mask = 1; mask <= 8; mask <<= 1) {
    #pragma unroll
    for (int reg = 0; reg < 4; ++reg)
      ldr[reg] += __shfl_xor(ldr[reg], mask, 64);
  }
  if (col == 0) {
    #pragma unroll
    for (int reg = 0; reg < 4; ++reg)
      ldp[dc][row0 + reg] = ldr[reg];
  }

  __syncthreads();                 // B5: z + ld partials done

  // ---- ld: complete 64-d sum per row ----
  if (t < 16)
    out[(size_t)B * 64 + b0 + t] =
        (ldp[0][t] + ldp[1][t]) + (ldp[2][t] + ldp[3][t]);

  // ---- coalesced z write: 16 rows x 64 cols, 1 float4/thread ----
  {
    const int rr = t >> 4, c4 = (t & 15) * 4;
    const float4 v = make_float4(h2s[rr][c4 + 0], h2s[rr][c4 + 1],
                                 h2s[rr][c4 + 2], h2s[rr][c4 + 3]);
    *reinterpret_cast<float4*>(out + (size_t)(b0 + rr) * 64 + c4) = v;
  }
}

extern "C" void kernel_launch(void* const* d_in, const int* in_sizes, int n_in,
                              void* d_out, int out_size, void* d_ws, size_t ws_size,
                              hipStream_t stream) {
  const float* x  = (const float*)d_in[0];
  const float* W1 = (const float*)d_in[1];
  const float* b1 = (const float*)d_in[2];
  const float* W2 = (const float*)d_in[3];
  const float* b2 = (const float*)d_in[4];
  const float* W3 = (const float*)d_in[5];
  const float* b3 = (const float*)d_in[6];
  float* out = (float*)d_out;
  char* ws   = (char*)d_ws;

  unsigned short* B1hi = (unsigned short*)(ws);           // 4096 u16
  unsigned short* B2hi = (unsigned short*)(ws + 8192);    // 2048 u16
  unsigned short* B3hi = (unsigned short*)(ws + 16384);   // 47104 u16

  const int B = in_sizes[0] / 64;        // 32768

  prep_kernel<<<184, 256, 0, stream>>>(W1, W2, W3, B1hi, B2hi, B3hi);

  fused_kernel<<<B / 16, 256, 0, stream>>>(
      x, B1hi, b1, B2hi, b2, B3hi, b3, out, B);
}

// Round 11
// 103.511 us; speedup vs baseline: 1.0547x; 1.0271x over previous
//
#include <hip/hip_runtime.h>

#define NM 23        // 3*K - 1, K = 8

typedef short short8 __attribute__((ext_vector_type(8)));
typedef float f32x4 __attribute__((ext_vector_type(4)));

#define LOG2E 1.44269504088896340736f

__device__ __forceinline__ float softplus_f(float v) {
  return fmaxf(v, 0.f) + __logf(1.f + __expf(-fabsf(v)));
}

__device__ __forceinline__ float fastrcp(float v) {
  return __builtin_amdgcn_rcpf(v);   // v_rcp_f32, ~1-2 ulp
}

__device__ __forceinline__ unsigned short bf16_rne(float x) {
  unsigned u = __float_as_uint(x);
  u += 0x7FFFu + ((u >> 16) & 1u);
  return (unsigned short)(u >> 16);
}

// ---------------------------------------------------------------------------
// Prep (R24-validated): Bhi-only fragments (B low word dropped).
// W3 rows m<16 pre-scaled by log2(e) -> exp2 domain.
// Fragment layout: B[k][n], n = ntile*16 + (lane&15),
// k = kstep*32 + (lane>>4)*8 + j, stored at ((ntile*nk+kstep)*64+lane)*8+j.
// ---------------------------------------------------------------------------
__global__ __launch_bounds__(256) void prep_kernel(
    const float* __restrict__ W1, const float* __restrict__ W2,
    const float* __restrict__ W3,
    unsigned short* __restrict__ B1hi,
    unsigned short* __restrict__ B2hi,
    unsigned short* __restrict__ B3hi) {
  const int idx = blockIdx.x * 256 + threadIdx.x;
  const int j = idx & 7, lane = (idx >> 3) & 63;
  const int col = lane & 15, quad = lane >> 4;

  if (idx < 4096) {                     // W1 fragments: nt<4, kt<2
    const int rest = idx >> 9, kt = rest & 1, nt = rest >> 1;
    const int k = kt * 32 + quad * 8 + j;   // d
    const int n = nt * 16 + col;            // i
    const float v = ((n % 63) >= k) ? W1[n * 64 + k] : 0.f;
    B1hi[idx] = bf16_rne(v);
  }
  if (idx < 2048) {                     // W2 fragments: nt<2, kt<2
    const int rest = idx >> 9, kt = rest & 1, nt = rest >> 1;
    const int k = kt * 32 + quad * 8 + j;   // i
    const int n = nt * 16 + col;            // j
    const float v = ((k % 63) <= n) ? W2[n * 64 + k] : 0.f;
    B2hi[idx] = bf16_rne(v);
  }
  if (idx < 92 * 64 * 8) {              // W3 fragments
    const int nt = idx >> 9;
    const int n = nt * 16 + col;        // n = m*64 + d
    const int d = n & 63;
    const int m = n >> 6;
    const int k = quad * 8 + j;
    float v = (k < d) ? W3[(size_t)n * 32 + k] : 0.f;
    if (m < 16) v *= LOG2E;             // exp2 domain for softmax logits
    B3hi[idx] = bf16_rne(v);
  }
}

// f32x4 pair (LDS or global, 16B-aligned) -> bf16 RNE fragment (hi only)
__device__ __forceinline__ short8 cvt_hi(const float* src) {
  const f32x4 a0 = *reinterpret_cast<const f32x4*>(src);
  const f32x4 a1 = *reinterpret_cast<const f32x4*>(src + 4);
  const float af[8] = {a0.x, a0.y, a0.z, a0.w, a1.x, a1.y, a1.z, a1.w};
  short8 hi;
  #pragma unroll
  for (int j = 0; j < 8; ++j) hi[j] = (short)bf16_rne(af[j]);
  return hi;
}

// ---------------------------------------------------------------------------
// Fused kernel. R25 CHANGE (extend R24's validated precision trade — error
// contributions of A-lo and B-lo are symmetric, ~2^-9 rel/product; dropping
// B-lo doubled absmax 0.0156->0.03125 with 5.5x headroom left):
//   A-side LOW WORD DROPPED TOO -> pure bf16 single-pass MFMA everywhere.
//   - MFMA issue halves again (L3: 46 -> 23 per wave).
//   - cvt_hilo (RNE-hi + reconstruct + sub + RNE-lo, ~64 VALU) -> cvt_hi
//     plain RNE pack (~24 VALU); 5 call sites, each on the dependent path
//     in front of an MFMA group — shortens every phase's serial prologue.
//   - alo registers gone (-8 VGPR live).
// Expected absmax ~0.0625 (2x R24), threshold 0.1725. Fallback if ld's
// 64-term sum accumulates worse: restore hi/lo on the D-group only.
// All control flow, barriers, and spline math identical to R24 (validated).
// ---------------------------------------------------------------------------
__global__ __launch_bounds__(256, 4) void fused_kernel(
    const float* __restrict__ x,
    const unsigned short* __restrict__ B1hi,
    const float* __restrict__ b1,
    const unsigned short* __restrict__ B2hi,
    const float* __restrict__ b2,
    const unsigned short* __restrict__ B3hi,
    const float* __restrict__ b3,
    float* __restrict__ out, int B) {
  __shared__ float h1s[16][68];    // stride 68: 16B-aligned b128 A-frag reads
  __shared__ float h2s[16][68];    // h2 (cols 0..31) -> z (cols 0..63)
  __shared__ float b3s[64 * NM];   // biases [d][m], W/H pre-scaled by log2e
  __shared__ float ldp[4][16];     // per-dc log-det partials

  const int t = threadIdx.x;
  const int b0 = blockIdx.x * 16;

  // ---- stage b3: b3s[d*NM+m] = b3[m*64+d] (*log2e for m<16) ----
  for (int idx = t; idx < 64 * NM; idx += 256) {
    const int dl = idx / NM, m = idx - dl * NM;
    const float s = (m < 16) ? LOG2E : 1.f;
    b3s[idx] = b3[m * 64 + dl] * s;
  }
  __syncthreads();                 // B1: b3 staged

  const int lane = t & 63;
  const int wv   = __builtin_amdgcn_readfirstlane(t >> 6);  // wave 0..3
  const int col  = lane & 15;
  const int quad = lane >> 4;

  // ---- layer 1 (MFMA): tile nt1 = wv, A-frags from global x ----
  {
    const int nt1 = wv;
    const float* xrow = x + (size_t)(b0 + col) * 64;
    short8 ah[2];
    #pragma unroll
    for (int kt = 0; kt < 2; ++kt)
      ah[kt] = cvt_hi(xrow + kt * 32 + quad * 8);

    const float bv = b1[nt1 * 16 + col];
    f32x4 acc = {bv, bv, bv, bv};
    #pragma unroll
    for (int kt = 0; kt < 2; ++kt) {
      const size_t off = ((size_t)(nt1 * 2 + kt) * 64 + lane) * 8;
      const short8 bh = *reinterpret_cast<const short8*>(B1hi + off);
      acc = __builtin_amdgcn_mfma_f32_16x16x32_bf16(ah[kt], bh, acc, 0, 0, 0);
    }
    #pragma unroll
    for (int reg = 0; reg < 4; ++reg)
      h1s[quad * 4 + reg][nt1 * 16 + col] = fmaxf(acc[reg], 0.f);
  }
  __syncthreads();                 // B2: h1 complete

  // ---- layer 2 (MFMA): tile nt2, waves 0..1 ----
  if (wv < 2) {
    const int nt2 = wv;
    short8 ah[2];
    #pragma unroll
    for (int kt = 0; kt < 2; ++kt)
      ah[kt] = cvt_hi(&h1s[col][kt * 32 + quad * 8]);

    const float bv = b2[nt2 * 16 + col];
    f32x4 acc = {bv, bv, bv, bv};
    #pragma unroll
    for (int kt = 0; kt < 2; ++kt) {
      const size_t off = ((size_t)(nt2 * 2 + kt) * 64 + lane) * 8;
      const short8 bh = *reinterpret_cast<const short8*>(B2hi + off);
      acc = __builtin_amdgcn_mfma_f32_16x16x32_bf16(ah[kt], bh, acc, 0, 0, 0);
    }
    #pragma unroll
    for (int reg = 0; reg < 4; ++reg)
      h2s[quad * 4 + reg][nt2 * 16 + col] = fmaxf(acc[reg], 0.f);
  }
  __syncthreads();                 // B3: h2 complete

  // ---- layer 3 setup: wave = dc; hoist A-frag + x before z writes ----
  const int dc = wv;
  const int row0 = quad * 4;
  const int d = dc * 16 + col;

  const short8 ah = cvt_hi(&h2s[col][quad * 8]);

  float xvv[4];
  #pragma unroll
  for (int reg = 0; reg < 4; ++reg)
    xvv[reg] = x[(size_t)(b0 + row0 + reg) * 64 + d];

  __syncthreads();                 // B4: A-frags hoisted; h2s free for z

  float ldr[4] = {0.f, 0.f, 0.f, 0.f};
  const float WSC = 1.0f - 1e-3f * 8.0f;

  float xcv[4], fidx[4], xkv[4], wkv[4], ykv[4], hkv[4];

  // ======== group W: m in [0,8) -> xc, idx, xk, wk ========
  {
    f32x4 acc[8];
    #pragma unroll
    for (int m = 0; m < 8; ++m) {
      const float bv = b3s[d * NM + m];
      acc[m] = (f32x4){bv, bv, bv, bv};
    }
    #pragma unroll
    for (int m = 0; m < 8; ++m) {
      const size_t off = ((size_t)(4 * m + dc) * 64 + lane) * 8;
      const short8 bh = *reinterpret_cast<const short8*>(B3hi + off);
      acc[m] = __builtin_amdgcn_mfma_f32_16x16x32_bf16(ah, bh, acc[m], 0, 0, 0);
    }
    #pragma unroll
    for (int reg = 0; reg < 4; ++reg) {
      float ew[8], sw = 0.f;
      #pragma unroll
      for (int k = 0; k < 8; ++k) { ew[k] = exp2f(acc[k][reg]); sw += ew[k]; }
      const float scale = 6.f * WSC * fastrcp(sw);
      float cumw[9];
      cumw[0] = -3.f;
      float prefE = 0.f;
      #pragma unroll
      for (int k = 0; k < 7; ++k) {
        prefE += ew[k];
        const float Ck = -3.f + 6e-3f * (float)(k + 1);
        cumw[k + 1] = fmaf(prefE, scale, Ck);
      }
      cumw[8] = 3.f;

      const float xv = xvv[reg];
      const float xc = fminf(fmaxf(xv, -3.f), 3.f);
      float fi = 0.f, xk = cumw[0], xk1 = cumw[1];
      #pragma unroll
      for (int k = 1; k < 8; ++k) {
        const bool s = xc >= cumw[k] + 1e-6f;
        xk  = s ? cumw[k]     : xk;
        xk1 = s ? cumw[k + 1] : xk1;
        fi  = s ? (float)k    : fi;
      }
      xcv[reg] = xc; fidx[reg] = fi; xkv[reg] = xk; wkv[reg] = xk1 - xk;
    }
  }

  // ======== group H: m in [8,16) -> yk, hk ========
  {
    f32x4 acc[8];
    #pragma unroll
    for (int m = 0; m < 8; ++m) {
      const float bv = b3s[d * NM + (8 + m)];
      acc[m] = (f32x4){bv, bv, bv, bv};
    }
    #pragma unroll
    for (int m = 0; m < 8; ++m) {
      const size_t off = ((size_t)(4 * (8 + m) + dc) * 64 + lane) * 8;
      const short8 bh = *reinterpret_cast<const short8*>(B3hi + off);
      acc[m] = __builtin_amdgcn_mfma_f32_16x16x32_bf16(ah, bh, acc[m], 0, 0, 0);
    }
    #pragma unroll
    for (int reg = 0; reg < 4; ++reg) {
      float eh[8], sh = 0.f;
      #pragma unroll
      for (int k = 0; k < 8; ++k) { eh[k] = exp2f(acc[k][reg]); sh += eh[k]; }
      const float scale = 6.f * WSC * fastrcp(sh);
      float cumh[9];
      cumh[0] = -3.f;
      float prefE = 0.f;
      #pragma unroll
      for (int k = 0; k < 7; ++k) {
        prefE += eh[k];
        const float Ck = -3.f + 6e-3f * (float)(k + 1);
        cumh[k + 1] = fmaf(prefE, scale, Ck);
      }
      cumh[8] = 3.f;

      float yk = cumh[0], yk1 = cumh[1];
      #pragma unroll
      for (int k = 1; k < 8; ++k) {
        const bool s = fidx[reg] >= (float)k;
        yk  = s ? cumh[k]     : yk;
        yk1 = s ? cumh[k + 1] : yk1;
      }
      ykv[reg] = yk; hkv[reg] = yk1 - yk;
    }
  }

  // ======== group D: m in [16,23) -> dk, dk1 + final spline ========
  {
    f32x4 acc[7];
    #pragma unroll
    for (int m = 0; m < 7; ++m) {
      const float bv = b3s[d * NM + (16 + m)];
      acc[m] = (f32x4){bv, bv, bv, bv};
    }
    #pragma unroll
    for (int m = 0; m < 7; ++m) {
      const size_t off = ((size_t)(4 * (16 + m) + dc) * 64 + lane) * 8;
      const short8 bh = *reinterpret_cast<const short8*>(B3hi + off);
      acc[m] = __builtin_amdgcn_mfma_f32_16x16x32_bf16(ah, bh, acc[m], 0, 0, 0);
    }
    #pragma unroll
    for (int reg = 0; reg < 4; ++reg) {
      float p[7];
      #pragma unroll
      for (int k = 0; k < 7; ++k) p[k] = acc[k][reg];
      const float fi = fidx[reg];

      // dk  = idx==0 ? 1 : 1e-3+sp(p[idx-1]);  dk1 = idx==7 ? 1 : 1e-3+sp(p[idx])
      float pa = p[0], pb = p[0];
      #pragma unroll
      for (int k = 2; k < 8; ++k) pa = (fi >= (float)k) ? p[k - 1] : pa;
      #pragma unroll
      for (int k = 1; k < 7; ++k) pb = (fi >= (float)k) ? p[k] : pb;
      const float spa = 1e-3f + softplus_f(pa);
      const float spb = 1e-3f + softplus_f(pb);
      const float dk  = (fi >= 0.5f) ? spa : 1.f;
      const float dk1 = (fi >= 6.5f) ? 1.f : spb;

      const float xc = xcv[reg], xk = xkv[reg], wk = wkv[reg];
      const float yk = ykv[reg], hk = hkv[reg];
      const float invwk = fastrcp(wk);
      const float delta = hk * invwk;
      const float theta = (xc - xk) * invwk;
      const float omt = 1.f - theta;
      const float tt = theta * omt;
      const float th2 = theta * theta;
      const float num = hk * (delta * th2 + dk * tt);
      const float den = delta + (dk + dk1 - 2.f * delta) * tt;
      const float rden = fastrcp(den);
      const float yv = yk + num * rden;
      const float dnum =
          delta * delta * (dk1 * th2 + 2.f * delta * tt + dk * omt * omt);
      const float ldv = __logf(dnum * rden * rden);

      const float xv = xvv[reg];
      const bool inside = (xv >= -3.f) && (xv <= 3.f);
      h2s[row0 + reg][d] = inside ? yv : xv;    // z into LDS (h2s reuse)
      ldr[reg] += inside ? ldv : 0.f;
    }
  }

  // ---- log-det: reduce this wave's 16 cols (lane bits 0..3) ----
  #pragma unroll
  for (int mask = 1; mask <= 8; mask <<= 1) {
    #pragma unroll
    for (int reg = 0; reg < 4; ++reg)
      ldr[reg] += __shfl_xor(ldr[reg], mask, 64);
  }
  if (col == 0) {
    #pragma unroll
    for (int reg = 0; reg < 4; ++reg)
      ldp[dc][row0 + reg] = ldr[reg];
  }

  __syncthreads();                 // B5: z + ld partials done

  // ---- ld: complete 64-d sum per row ----
  if (t < 16)
    out[(size_t)B * 64 + b0 + t] =
        (ldp[0][t] + ldp[1][t]) + (ldp[2][t] + ldp[3][t]);

  // ---- coalesced z write: 16 rows x 64 cols, 1 float4/thread ----
  {
    const int rr = t >> 4, c4 = (t & 15) * 4;
    const float4 v = make_float4(h2s[rr][c4 + 0], h2s[rr][c4 + 1],
                                 h2s[rr][c4 + 2], h2s[rr][c4 + 3]);
    *reinterpret_cast<float4*>(out + (size_t)(b0 + rr) * 64 + c4) = v;
  }
}

extern "C" void kernel_launch(void* const* d_in, const int* in_sizes, int n_in,
                              void* d_out, int out_size, void* d_ws, size_t ws_size,
                              hipStream_t stream) {
  const float* x  = (const float*)d_in[0];
  const float* W1 = (const float*)d_in[1];
  const float* b1 = (const float*)d_in[2];
  const float* W2 = (const float*)d_in[3];
  const float* b2 = (const float*)d_in[4];
  const float* W3 = (const float*)d_in[5];
  const float* b3 = (const float*)d_in[6];
  float* out = (float*)d_out;
  char* ws   = (char*)d_ws;

  unsigned short* B1hi = (unsigned short*)(ws);           // 4096 u16
  unsigned short* B2hi = (unsigned short*)(ws + 8192);    // 2048 u16
  unsigned short* B3hi = (unsigned short*)(ws + 16384);   // 47104 u16

  const int B = in_sizes[0] / 64;        // 32768

  prep_kernel<<<184, 256, 0, stream>>>(W1, W2, W3, B1hi, B2hi, B3hi);

  fused_kernel<<<B / 16, 256, 0, stream>>>(
      x, B1hi, b1, B2hi, b2, B3hi, b3, out, B);
}